// Round 1
// baseline (57.497 us; speedup 1.0000x reference)
//
#include <hip/hip_runtime.h>

#define MARGIN 500.0f

__global__ __launch_bounds__(256) void custom_loss_kernel(
        const int* __restrict__ labels,
        const float* __restrict__ coords,
        float* __restrict__ out, int N) {
    // Anchor = last element. L2 broadcasts these reads across all waves.
    const int   anchor_lab = labels[N - 1];
    const float ax = coords[3 * (N - 1) + 0];
    const float ay = coords[3 * (N - 1) + 1];
    const float az = coords[3 * (N - 1) + 2];

    const int i = blockIdx.x * blockDim.x + threadIdx.x;
    float v = 0.0f;
    if (i < N) {
        const float dx = ax - coords[3 * i + 0];
        const float dy = ay - coords[3 * i + 1];
        const float dz = az - coords[3 * i + 2];
        const float dist = dx * dx + dy * dy + dz * dz;
        v = (labels[i] == anchor_lab) ? dist : fmaxf(0.0f, MARGIN - dist);
    }

    // Wave-64 butterfly reduction.
    #pragma unroll
    for (int off = 32; off > 0; off >>= 1)
        v += __shfl_down(v, off, 64);

    __shared__ float smem[4];  // 256 threads = 4 waves
    const int wave = threadIdx.x >> 6;
    const int lane = threadIdx.x & 63;
    if (lane == 0) smem[wave] = v;
    __syncthreads();

    if (threadIdx.x == 0) {
        const float s = smem[0] + smem[1] + smem[2] + smem[3];
        atomicAdd(out, s);  // device-scope by default on CDNA
    }
}

extern "C" void kernel_launch(void* const* d_in, const int* in_sizes, int n_in,
                              void* d_out, int out_size, void* d_ws, size_t ws_size,
                              hipStream_t stream) {
    const int*   labels = (const int*)d_in[0];
    const float* coords = (const float*)d_in[1];
    float*       out    = (float*)d_out;
    const int N = in_sizes[0];

    // Harness re-poisons d_out with 0xAA before every timed replay;
    // zero it on-stream (memset node is graph-capturable).
    hipMemsetAsync(out, 0, sizeof(float), stream);

    const int block = 256;
    const int grid  = (N + block - 1) / block;  // 128 blocks
    custom_loss_kernel<<<grid, block, 0, stream>>>(labels, coords, out, N);
}